// Round 2
// baseline (596.434 us; speedup 1.0000x reference)
//
#include <hip/hip_runtime.h>

typedef __bf16 bf16_t;
typedef __bf16 bf16x8 __attribute__((ext_vector_type(8)));
typedef __bf16 bf16x4 __attribute__((ext_vector_type(4)));
typedef float  f32x4  __attribute__((ext_vector_type(4)));

#define MFMA16(a,b,c) __builtin_amdgcn_mfma_f32_16x16x32_bf16((a),(b),(c),0,0,0)

// ---------- LDS helpers with XOR swizzle (byte ^= (row&7)<<4) ----------
__device__ __forceinline__ bf16x8 lds_read8(const bf16_t* base, int row, int k, int rowB) {
    int byte = row * rowB + (k << 1);
    byte ^= ((row & 7) << 4);
    return *(const bf16x8*)((const char*)base + byte);
}
__device__ __forceinline__ void lds_write1(bf16_t* base, int row, int col, int rowB, float v) {
    int byte = row * rowB + (col << 1);
    byte ^= ((row & 7) << 4);
    *(bf16_t*)((char*)base + byte) = (bf16_t)v;
}
__device__ __forceinline__ void lds_write16B(bf16_t* base, int row, int colbyte, int rowB, bf16x8 v) {
    int byte = row * rowB + colbyte;
    byte ^= ((row & 7) << 4);
    *(bf16x8*)((char*)base + byte) = v;
}
__device__ __forceinline__ bf16x8 lds_read16B(const bf16_t* base, int row, int colbyte, int rowB) {
    int byte = row * rowB + colbyte;
    byte ^= ((row & 7) << 4);
    return *(const bf16x8*)((const char*)base + byte);
}

// ---------- split-buffer (two 64x256 halves, rowB=512B) helpers ----------
__device__ __forceinline__ bf16x8 lds_read8h(const bf16_t* half, int row, int kk) {
    int byte = (row << 9) + (kk << 1);
    byte ^= ((row & 7) << 4);
    return *(const bf16x8*)((const char*)half + byte);
}
__device__ __forceinline__ void lds_write1h(bf16_t* half, int row, int cc, float v) {
    int byte = (row << 9) + (cc << 1);
    byte ^= ((row & 7) << 4);
    *(bf16_t*)((char*)half + byte) = (bf16_t)v;
}
__device__ __forceinline__ float lds_read1h(const bf16_t* half, int row, int cc) {
    int byte = (row << 9) + (cc << 1);
    byte ^= ((row & 7) << 4);
    return (float)*(const bf16_t*)((const char*)half + byte);
}

// accumulate a 64x64 per-wave tile over K=512 from split LDS halves
__device__ __forceinline__ void gemm_acc512(f32x4 (&acc)[4][4],
    const bf16_t* bufA, const bf16_t* bufB,
    const bf16_t* __restrict__ Wb, int n0, int l15, int lhi)
{
    for (int k0 = 0; k0 < 512; k0 += 32) {
        const bf16_t* base = (k0 < 256) ? bufA : bufB;   // wave-uniform
        const int kk = (k0 & 255) + lhi * 8;
        const int kg = k0 + lhi * 8;
        bf16x8 a[4], b[4];
#pragma unroll
        for (int rf = 0; rf < 4; ++rf)
            a[rf] = lds_read8h(base, rf * 16 + l15, kk);
#pragma unroll
        for (int cf = 0; cf < 4; ++cf)
            b[cf] = *(const bf16x8*)(Wb + (size_t)(n0 + cf * 16 + l15) * 512 + kg);
#pragma unroll
        for (int rf = 0; rf < 4; ++rf)
#pragma unroll
            for (int cf = 0; cf < 4; ++cf)
                acc[rf][cf] = MFMA16(a[rf], b[cf], acc[rf][cf]);
    }
}

template<bool RELU>
__device__ __forceinline__ void epi_to_lds(const f32x4 (&acc)[4][4], const float* __restrict__ bias,
    bf16_t* bufA, bf16_t* bufB, int n0, int l15, int lhi)
{
    bf16_t* half = (n0 < 256) ? bufA : bufB;             // wave-uniform
    const int c0 = n0 & 255;
#pragma unroll
    for (int cf = 0; cf < 4; ++cf) {
        const int col = n0 + cf * 16 + l15;
        const float bs = bias[col];
#pragma unroll
        for (int rf = 0; rf < 4; ++rf)
#pragma unroll
            for (int r = 0; r < 4; ++r) {
                float v = acc[rf][cf][r] + bs;
                if (RELU) v = fmaxf(v, 0.0f);
                lds_write1h(half, rf * 16 + lhi * 4 + r, c0 + cf * 16 + l15, v);
            }
    }
}

__device__ __forceinline__ void epi_to_global(const f32x4 (&acc)[4][4], const float* __restrict__ bias,
    float* __restrict__ gout, long row0, int n0, int l15, int lhi)
{
#pragma unroll
    for (int cf = 0; cf < 4; ++cf) {
        const int col = n0 + cf * 16 + l15;
        const float bs = bias[col];
#pragma unroll
        for (int rf = 0; rf < 4; ++rf)
#pragma unroll
            for (int r = 0; r < 4; ++r)
                gout[(row0 + rf * 16 + lhi * 4 + r) * 512 + col] = acc[rf][cf][r] + bs;
    }
}

// ---------- kernel 1: cast all weights to bf16 into ws ----------
__global__ __launch_bounds__(256) void cast_kernel(
    const float* __restrict__ W1, const float* __restrict__ W2,
    const float* __restrict__ muW, const float* __restrict__ lvW,
    const float* __restrict__ Wqkv, const float* __restrict__ Wo,
    const float* __restrict__ Wc, const float* __restrict__ Wd1,
    const float* __restrict__ Wd2, const float* __restrict__ Wd3,
    bf16_t* __restrict__ dst)
{
    int i = blockIdx.x * 256 + threadIdx.x;   // grid exactly covers 1376256
    const float* src; int off;
    if      (i <  262144) { src = W1;   off = 0; }
    else if (i <  524288) { src = W2;   off = 262144; }
    else if (i <  655360) { src = muW;  off = 524288; }
    else if (i <  786432) { src = lvW;  off = 655360; }
    else if (i <  798720) { src = Wqkv; off = 786432; }
    else if (i <  802816) { src = Wo;   off = 798720; }
    else if (i <  819200) { src = Wc;   off = 802816; }
    else if (i <  851968) { src = Wd1;  off = 819200; }
    else if (i < 1114112) { src = Wd2;  off = 851968; }
    else                  { src = Wd3;  off = 1114112; }
    dst[i] = (bf16_t)src[i - off];
}

// ---------- kernel 2: encoder + heads + reparameterize (72->64KB LDS, 2 blk/CU) ----------
__global__ __launch_bounds__(512, 4) void enc_kernel(
    const float* __restrict__ x, const float* __restrict__ eps,
    const bf16_t* __restrict__ W1b, const float* __restrict__ b1,
    const bf16_t* __restrict__ W2b, const float* __restrict__ b2,
    const bf16_t* __restrict__ Hb,  const float* __restrict__ mub,
    const float* __restrict__ lvb,  bf16_t* __restrict__ zout)
{
    __shared__ bf16_t bufA[64 * 256];   // 32KB: cols 0-255
    __shared__ bf16_t bufB[64 * 256];   // 32KB: cols 256-511
    const int t = threadIdx.x;
    const size_t r0 = (size_t)blockIdx.x * 64;

    // stage x tile (fp32 -> bf16, split swizzled halves)
    for (int it = 0; it < 16; ++it) {
        int flat = it * 512 + t;
        int row = flat >> 7, c4 = flat & 127;
        float4 v = ((const float4*)(x + (r0 + row) * 512))[c4];
        bf16x4 h = { (bf16_t)v.x, (bf16_t)v.y, (bf16_t)v.z, (bf16_t)v.w };
        bf16_t* half = (c4 < 64) ? bufA : bufB;
        int byte = (row << 9) + ((c4 & 63) << 3);
        byte ^= ((row & 7) << 4);
        *(bf16x4*)((char*)half + byte) = h;
    }
    __syncthreads();
    const int wave = t >> 6, lane = t & 63, l15 = lane & 15, lhi = lane >> 4;
    const int n0 = wave * 64;

    {   // layer 1
        f32x4 acc[4][4] = {};
        gemm_acc512(acc, bufA, bufB, W1b, n0, l15, lhi);
        __syncthreads();                       // all reads of x done
        epi_to_lds<true>(acc, b1, bufA, bufB, n0, l15, lhi);
    }
    __syncthreads();
    {   // layer 2
        f32x4 acc[4][4] = {};
        gemm_acc512(acc, bufA, bufB, W2b, n0, l15, lhi);
        __syncthreads();
        epi_to_lds<true>(acc, b2, bufA, bufB, n0, l15, lhi);
    }
    __syncthreads();
    {   // heads: cols 0-255 mu, 256-511 lv
        f32x4 acc[4][4] = {};
        gemm_acc512(acc, bufA, bufB, Hb, n0, l15, lhi);
        __syncthreads();
        const float* hb = (wave < 4) ? mub : (lvb - 256);
        epi_to_lds<false>(acc, hb, bufA, bufB, n0, l15, lhi);
    }
    __syncthreads();

    // z = mu + eps * T^1.5 * exp(0.5*lv_raw)   (log-T folded); mu in bufA, lv in bufB
    const int c = t & 255;
    const int a = c >> 6;
    const float tp = (a == 0) ? 1.8371173070873836f
                   : (a == 1) ? 0.35355339059327373f
                   : (a == 2) ? 1.0f
                              : 0.7155417527999327f;
    for (int it = 0; it < 32; ++it) {
        int row = it * 2 + (t >> 8);
        float mu = lds_read1h(bufA, row, c);
        float lv = lds_read1h(bufB, row, c);
        float ep = eps[(r0 + row) * 256 + c];
        float zz = fmaf(ep * tp, expf(0.5f * lv), mu);
        zout[(r0 + row) * 256 + c] = (bf16_t)zz;
    }
}

// ---------- kernel 3: attention over 4 agents + consensus (unchanged) ----------
__global__ __launch_bounds__(512) void attn_kernel(
    const bf16_t* __restrict__ z,
    const bf16_t* __restrict__ Wqkvb, const float* __restrict__ bqkv,
    const bf16_t* __restrict__ Wob,   const float* __restrict__ bo,
    const bf16_t* __restrict__ Wcb,   const float* __restrict__ bc,
    bf16_t* __restrict__ zcb)
{
    __shared__ bf16_t zt[256 * 64];    // z tile, later ctx tile   (rowB 128)
    __shared__ bf16_t qt[256 * 192];   // qkv tile, later z_att    (rowB 384/128)
    const int t = threadIdx.x;
    const size_t s0 = (size_t)blockIdx.x * 64;

    for (int it = 0; it < 4; ++it) {
        int ch = it * 512 + t;
        int r = ch >> 3, cc = ch & 7;
        bf16x8 v = *(const bf16x8*)(z + s0 * 256 + r * 64 + cc * 8);
        lds_write16B(zt, r, cc * 16, 128, v);
    }
    __syncthreads();
    const int wave = t >> 6, lane = t & 63, l15 = lane & 15, lhi = lane >> 4;
    const int rbase = wave * 32;

    // qkv: (256 x 192) = zt (256x64) @ Wqkv^T
    for (int cc = 0; cc < 4; ++cc) {
        f32x4 acc[2][3] = {};
#pragma unroll
        for (int ks = 0; ks < 2; ++ks) {
            int k = ks * 32 + lhi * 8;
            bf16x8 a0 = lds_read8(zt, rbase + l15, k, 128);
            bf16x8 a1 = lds_read8(zt, rbase + 16 + l15, k, 128);
#pragma unroll
            for (int cf = 0; cf < 3; ++cf) {
                bf16x8 b = *(const bf16x8*)(Wqkvb + (cc * 48 + cf * 16 + l15) * 64 + k);
                acc[0][cf] = MFMA16(a0, b, acc[0][cf]);
                acc[1][cf] = MFMA16(a1, b, acc[1][cf]);
            }
        }
#pragma unroll
        for (int cf = 0; cf < 3; ++cf) {
            int col = cc * 48 + cf * 16 + l15;
            float bs = bqkv[col];
#pragma unroll
            for (int rf = 0; rf < 2; ++rf)
#pragma unroll
                for (int r = 0; r < 4; ++r)
                    lds_write1(qt, rbase + rf * 16 + lhi * 4 + r, col, 384, acc[rf][cf][r] + bs);
        }
    }
    __syncthreads();

    if (t < 256) {
        const int sl = t >> 2, head = t & 3;
        bf16x8 qv[4][2], kv[4][2], vv[4][2];
#pragma unroll
        for (int a2 = 0; a2 < 4; ++a2) {
            int r = sl * 4 + a2;
#pragma unroll
            for (int i = 0; i < 2; ++i) {
                qv[a2][i] = lds_read16B(qt, r, head * 32 + 16 * i, 384);
                kv[a2][i] = lds_read16B(qt, r, 128 + head * 32 + 16 * i, 384);
                vv[a2][i] = lds_read16B(qt, r, 256 + head * 32 + 16 * i, 384);
            }
        }
        float sc[4][4];
#pragma unroll
        for (int qa = 0; qa < 4; ++qa)
#pragma unroll
            for (int ka = 0; ka < 4; ++ka) {
                float s = 0.f;
#pragma unroll
                for (int i = 0; i < 2; ++i)
#pragma unroll
                    for (int j = 0; j < 8; ++j)
                        s += (float)qv[qa][i][j] * (float)kv[ka][i][j];
                sc[qa][ka] = s * 0.25f;
            }
#pragma unroll
        for (int qa = 0; qa < 4; ++qa) {
            float m = fmaxf(fmaxf(sc[qa][0], sc[qa][1]), fmaxf(sc[qa][2], sc[qa][3]));
            float e[4], sum = 0.f;
#pragma unroll
            for (int ka = 0; ka < 4; ++ka) { e[ka] = expf(sc[qa][ka] - m); sum += e[ka]; }
            float inv = 1.f / sum;
#pragma unroll
            for (int i = 0; i < 2; ++i) {
                bf16x8 cv;
#pragma unroll
                for (int j = 0; j < 8; ++j) {
                    float cval = 0.f;
#pragma unroll
                    for (int ka = 0; ka < 4; ++ka) cval += e[ka] * inv * (float)vv[ka][i][j];
                    cv[j] = (bf16_t)cval;
                }
                lds_write16B(zt, sl * 4 + qa, head * 32 + 16 * i, 128, cv);
            }
        }
    }
    __syncthreads();

    {   // z_att = ctx @ Wo^T + bo
        f32x4 acc[2][4] = {};
#pragma unroll
        for (int ks = 0; ks < 2; ++ks) {
            int k = ks * 32 + lhi * 8;
            bf16x8 a0 = lds_read8(zt, rbase + l15, k, 128);
            bf16x8 a1 = lds_read8(zt, rbase + 16 + l15, k, 128);
#pragma unroll
            for (int cf = 0; cf < 4; ++cf) {
                bf16x8 b = *(const bf16x8*)(Wob + (cf * 16 + l15) * 64 + k);
                acc[0][cf] = MFMA16(a0, b, acc[0][cf]);
                acc[1][cf] = MFMA16(a1, b, acc[1][cf]);
            }
        }
        __syncthreads();
#pragma unroll
        for (int cf = 0; cf < 4; ++cf) {
            int col = cf * 16 + l15;
            float bs = bo[col];
#pragma unroll
            for (int rf = 0; rf < 2; ++rf)
#pragma unroll
                for (int r = 0; r < 4; ++r)
                    lds_write1(qt, rbase + rf * 16 + lhi * 4 + r, col, 128, acc[rf][cf][r] + bs);
        }
    }
    __syncthreads();

    {   // z_consensus = z_att.reshape(64,256) @ Wc^T + bc
        f32x4 acc2[2] = {};
        const int rfw = wave >> 1, cbase = (wave & 1) * 2;
        const int srow = rfw * 16 + l15;
#pragma unroll
        for (int ks = 0; ks < 8; ++ks) {
            int k = ks * 32 + lhi * 8;
            int byte = (srow << 9) + (k << 1);
            byte ^= ((((srow << 2) + (k >> 6)) & 7) << 4);
            bf16x8 a = *(const bf16x8*)((const char*)qt + byte);
#pragma unroll
            for (int i = 0; i < 2; ++i) {
                bf16x8 b = *(const bf16x8*)(Wcb + ((cbase + i) * 16 + l15) * 256 + k);
                acc2[i] = MFMA16(a, b, acc2[i]);
            }
        }
#pragma unroll
        for (int i = 0; i < 2; ++i) {
            int col = (cbase + i) * 16 + l15;
            float bs = bc[col];
#pragma unroll
            for (int r = 0; r < 4; ++r) {
                int s = (int)(s0) + rfw * 16 + lhi * 4 + r;
                zcb[(size_t)s * 64 + col] = (bf16_t)(acc2[i][r] + bs);
            }
        }
    }
}

// ---------- kernel 4: fused 3-layer decoder (72KB LDS, 2 blk/CU) ----------
__global__ __launch_bounds__(512, 4) void dec_kernel(
    const bf16_t* __restrict__ z, const bf16_t* __restrict__ zc,
    const bf16_t* __restrict__ Wd1b, const float* __restrict__ bd1,
    const bf16_t* __restrict__ Wd2b, const float* __restrict__ bd2,
    const bf16_t* __restrict__ Wd3b, const float* __restrict__ bd3,
    float* __restrict__ out)
{
    __shared__ bf16_t zz[64 * 64];      // 8KB latent tile
    __shared__ bf16_t bufA[64 * 256];   // 32KB cols 0-255
    __shared__ bf16_t bufB[64 * 256];   // 32KB cols 256-511
    const int t = threadIdx.x;
    const long r0 = (long)blockIdx.x * 64;

    {   // gather latent rows: row = s*5 + j; j==0 -> consensus, else agent j-1
        int row = t >> 3, ch = t & 7;
        long rg = r0 + row;
        int s = (int)(rg / 5);
        int j = (int)(rg - (long)s * 5);
        const bf16_t* src = (j == 0) ? (zc + (size_t)s * 64)
                                     : (z + (size_t)s * 256 + (j - 1) * 64);
        bf16x8 v = *(const bf16x8*)(src + ch * 8);
        int byte = (row << 7) + (ch << 4);
        byte ^= ((row & 7) << 4);
        *(bf16x8*)((char*)zz + byte) = v;
    }
    __syncthreads();
    const int wave = t >> 6, lane = t & 63, l15 = lane & 15, lhi = lane >> 4;
    const int n0 = wave * 64;

    {   // layer 1: K=64 from zz
        f32x4 acc[4][4] = {};
        for (int k0 = 0; k0 < 64; k0 += 32) {
            const int k = k0 + lhi * 8;
            bf16x8 a[4], b[4];
#pragma unroll
            for (int rf = 0; rf < 4; ++rf)
                a[rf] = lds_read8(zz, rf * 16 + l15, k, 128);
#pragma unroll
            for (int cf = 0; cf < 4; ++cf)
                b[cf] = *(const bf16x8*)(Wd1b + (n0 + cf * 16 + l15) * 64 + k);
#pragma unroll
            for (int rf = 0; rf < 4; ++rf)
#pragma unroll
                for (int cf = 0; cf < 4; ++cf)
                    acc[rf][cf] = MFMA16(a[rf], b[cf], acc[rf][cf]);
        }
        epi_to_lds<true>(acc, bd1, bufA, bufB, n0, l15, lhi);
    }
    __syncthreads();
    {   // layer 2
        f32x4 acc[4][4] = {};
        gemm_acc512(acc, bufA, bufB, Wd2b, n0, l15, lhi);
        __syncthreads();                  // all reads of act1 done
        epi_to_lds<true>(acc, bd2, bufA, bufB, n0, l15, lhi);
    }
    __syncthreads();
    {   // layer 3 -> global fp32
        f32x4 acc[4][4] = {};
        gemm_acc512(acc, bufA, bufB, Wd3b, n0, l15, lhi);
        epi_to_global(acc, bd3, out, r0, n0, l15, lhi);
    }
}

// ---------- launcher ----------
extern "C" void kernel_launch(void* const* d_in, const int* in_sizes, int n_in,
                              void* d_out, int out_size, void* d_ws, size_t ws_size,
                              hipStream_t stream) {
    const float* x    = (const float*)d_in[0];
    const float* eps  = (const float*)d_in[1];
    const float* W1   = (const float*)d_in[2];
    const float* b1   = (const float*)d_in[3];
    const float* W2   = (const float*)d_in[4];
    const float* b2   = (const float*)d_in[5];
    const float* muW  = (const float*)d_in[6];
    const float* mub  = (const float*)d_in[7];
    const float* lvW  = (const float*)d_in[8];
    const float* lvb  = (const float*)d_in[9];
    const float* Wqkv = (const float*)d_in[10];
    const float* bqkv = (const float*)d_in[11];
    const float* Wo   = (const float*)d_in[12];
    const float* bo   = (const float*)d_in[13];
    const float* Wc   = (const float*)d_in[14];
    const float* bc   = (const float*)d_in[15];
    const float* Wd1  = (const float*)d_in[16];
    const float* bd1  = (const float*)d_in[17];
    const float* Wd2  = (const float*)d_in[18];
    const float* bd2  = (const float*)d_in[19];
    const float* Wd3  = (const float*)d_in[20];
    const float* bd3  = (const float*)d_in[21];
    float* out = (float*)d_out;

    bf16_t* wsb  = (bf16_t*)d_ws;
    bf16_t* W1b  = wsb + 0;
    bf16_t* W2b  = wsb + 262144;
    bf16_t* Hb   = wsb + 524288;    // [muW(256x512) ; lvW(256x512)]
    bf16_t* Wqkvb= wsb + 786432;
    bf16_t* Wob  = wsb + 798720;
    bf16_t* Wcb  = wsb + 802816;
    bf16_t* Wd1b = wsb + 819200;
    bf16_t* Wd2b = wsb + 851968;
    bf16_t* Wd3b = wsb + 1114112;
    bf16_t* zbuf = wsb + 1376256;   // (B,256) bf16
    bf16_t* zcb  = wsb + 9764864;   // (B,64)  bf16

    cast_kernel<<<dim3(5376), dim3(256), 0, stream>>>(
        W1, W2, muW, lvW, Wqkv, Wo, Wc, Wd1, Wd2, Wd3, wsb);
    enc_kernel<<<dim3(512), dim3(512), 0, stream>>>(
        x, eps, W1b, b1, W2b, b2, Hb, mub, lvb, zbuf);
    attn_kernel<<<dim3(512), dim3(512), 0, stream>>>(
        zbuf, Wqkvb, bqkv, Wob, bo, Wcb, bc, zcb);
    dec_kernel<<<dim3(2560), dim3(512), 0, stream>>>(
        zbuf, zcb, Wd1b, bd1, Wd2b, bd2, Wd3b, bd3, out);
}

// Round 3
// 534.217 us; speedup vs baseline: 1.1165x; 1.1165x over previous
//
#include <hip/hip_runtime.h>

typedef __bf16 bf16_t;
typedef __bf16 bf16x8 __attribute__((ext_vector_type(8)));
typedef __bf16 bf16x4 __attribute__((ext_vector_type(4)));
typedef float  f32x4  __attribute__((ext_vector_type(4)));

#define MFMA16(a,b,c) __builtin_amdgcn_mfma_f32_16x16x32_bf16((a),(b),(c),0,0,0)

// ---------- LDS helpers with XOR swizzle (byte ^= (row&7)<<4) ----------
__device__ __forceinline__ bf16x8 lds_read8(const bf16_t* base, int row, int k, int rowB) {
    int byte = row * rowB + (k << 1);
    byte ^= ((row & 7) << 4);
    return *(const bf16x8*)((const char*)base + byte);
}
__device__ __forceinline__ void lds_write8B(bf16_t* base, int row, int col, int rowB, bf16x4 v) {
    int byte = row * rowB + (col << 1);
    byte ^= ((row & 7) << 4);
    *(bf16x4*)((char*)base + byte) = v;
}
__device__ __forceinline__ bf16x4 lds_read8B(const bf16_t* base, int row, int col, int rowB) {
    int byte = row * rowB + (col << 1);
    byte ^= ((row & 7) << 4);
    return *(const bf16x4*)((const char*)base + byte);
}
__device__ __forceinline__ void lds_write1(bf16_t* base, int row, int col, int rowB, float v) {
    int byte = row * rowB + (col << 1);
    byte ^= ((row & 7) << 4);
    *(bf16_t*)((char*)base + byte) = (bf16_t)v;
}
__device__ __forceinline__ void lds_write16B(bf16_t* base, int row, int colbyte, int rowB, bf16x8 v) {
    int byte = row * rowB + colbyte;
    byte ^= ((row & 7) << 4);
    *(bf16x8*)((char*)base + byte) = v;
}
__device__ __forceinline__ bf16x8 lds_read16B(const bf16_t* base, int row, int colbyte, int rowB) {
    int byte = row * rowB + colbyte;
    byte ^= ((row & 7) << 4);
    return *(const bf16x8*)((const char*)base + byte);
}

// ---------- K-looped 64x64 per-wave tile with 2-deep B register prefetch ----------
// SWAPPED operands: MFMA16(b, a, acc) -> acc[rf][cf][r] = C[rf*16+l15][n0+cf*16+lhi*4+r]
template<int K>
__device__ __forceinline__ void gemm_tile(f32x4 (&acc)[4][4],
    const bf16_t* act, int rowB, const bf16_t* __restrict__ W,
    int n0, int l15, int lhi)
{
    constexpr int NS = K / 32;
    const bf16_t* wp = W + (size_t)(n0 + l15) * K + lhi * 8;
    bf16x8 bpf0[4], bpf1[4];
#pragma unroll
    for (int cf = 0; cf < 4; ++cf) bpf0[cf] = *(const bf16x8*)(wp + cf * 16 * K);
#pragma unroll
    for (int cf = 0; cf < 4; ++cf) bpf1[cf] = (NS > 1) ? *(const bf16x8*)(wp + cf * 16 * K + 32) : bpf0[cf];
#pragma unroll
    for (int s = 0; s < NS; ++s) {
        bf16x8 a[4], bc[4];
#pragma unroll
        for (int cf = 0; cf < 4; ++cf) bc[cf] = (s & 1) ? bpf1[cf] : bpf0[cf];
        if (s + 2 < NS) {
#pragma unroll
            for (int cf = 0; cf < 4; ++cf) {
                bf16x8 nb = *(const bf16x8*)(wp + cf * 16 * K + (s + 2) * 32);
                if (s & 1) bpf1[cf] = nb; else bpf0[cf] = nb;
            }
        }
#pragma unroll
        for (int rf = 0; rf < 4; ++rf)
            a[rf] = lds_read8(act, rf * 16 + l15, s * 32 + lhi * 8, rowB);
#pragma unroll
        for (int rf = 0; rf < 4; ++rf)
#pragma unroll
            for (int cf = 0; cf < 4; ++cf)
                acc[rf][cf] = MFMA16(bc[cf], a[rf], acc[rf][cf]);
    }
}

template<bool RELU>
__device__ __forceinline__ void epi_lds(const f32x4 (&acc)[4][4], const float* __restrict__ bias,
    bf16_t* dst, int rowB, int n0, int l15, int lhi)
{
#pragma unroll
    for (int cf = 0; cf < 4; ++cf) {
        const int c0 = n0 + cf * 16 + lhi * 4;
        float4 b4 = *(const float4*)(bias + c0);
#pragma unroll
        for (int rf = 0; rf < 4; ++rf) {
            float v0 = acc[rf][cf][0] + b4.x;
            float v1 = acc[rf][cf][1] + b4.y;
            float v2 = acc[rf][cf][2] + b4.z;
            float v3 = acc[rf][cf][3] + b4.w;
            if (RELU) {
                v0 = fmaxf(v0, 0.f); v1 = fmaxf(v1, 0.f);
                v2 = fmaxf(v2, 0.f); v3 = fmaxf(v3, 0.f);
            }
            bf16x4 p = { (bf16_t)v0, (bf16_t)v1, (bf16_t)v2, (bf16_t)v3 };
            lds_write8B(dst, rf * 16 + l15, c0, rowB, p);
        }
    }
}

__device__ __forceinline__ void epi_global(const f32x4 (&acc)[4][4], const float* __restrict__ bias,
    float* __restrict__ out, long row0, int n0, int l15, int lhi)
{
#pragma unroll
    for (int cf = 0; cf < 4; ++cf) {
        const int c0 = n0 + cf * 16 + lhi * 4;
        float4 b4 = *(const float4*)(bias + c0);
#pragma unroll
        for (int rf = 0; rf < 4; ++rf) {
            float4 o = { acc[rf][cf][0] + b4.x, acc[rf][cf][1] + b4.y,
                         acc[rf][cf][2] + b4.z, acc[rf][cf][3] + b4.w };
            *(float4*)(out + (row0 + rf * 16 + l15) * 512 + c0) = o;
        }
    }
}

// ---------- kernel 1: cast all weights to bf16 into ws ----------
__global__ __launch_bounds__(256) void cast_kernel(
    const float* __restrict__ W1, const float* __restrict__ W2,
    const float* __restrict__ muW, const float* __restrict__ lvW,
    const float* __restrict__ Wqkv, const float* __restrict__ Wo,
    const float* __restrict__ Wc, const float* __restrict__ Wd1,
    const float* __restrict__ Wd2, const float* __restrict__ Wd3,
    bf16_t* __restrict__ dst)
{
    int i = blockIdx.x * 256 + threadIdx.x;   // grid exactly covers 1376256
    const float* src; int off;
    if      (i <  262144) { src = W1;   off = 0; }
    else if (i <  524288) { src = W2;   off = 262144; }
    else if (i <  655360) { src = muW;  off = 524288; }
    else if (i <  786432) { src = lvW;  off = 655360; }
    else if (i <  798720) { src = Wqkv; off = 786432; }
    else if (i <  802816) { src = Wo;   off = 798720; }
    else if (i <  819200) { src = Wc;   off = 802816; }
    else if (i <  851968) { src = Wd1;  off = 819200; }
    else if (i < 1114112) { src = Wd2;  off = 851968; }
    else                  { src = Wd3;  off = 1114112; }
    dst[i] = (bf16_t)src[i - off];
}

// ---------- kernel 2: encoder + heads + reparameterize ----------
__global__ __launch_bounds__(512, 2) void enc_kernel(
    const float* __restrict__ x, const float* __restrict__ eps,
    const bf16_t* __restrict__ W1b, const float* __restrict__ b1,
    const bf16_t* __restrict__ W2b, const float* __restrict__ b2,
    const bf16_t* __restrict__ Hb,  const float* __restrict__ mub,
    const float* __restrict__ lvb,  bf16_t* __restrict__ zout)
{
    __shared__ bf16_t bufA[64 * 512];   // ping
    __shared__ bf16_t bufB[64 * 512];   // pong
    const int t = threadIdx.x;
    const size_t r0 = (size_t)blockIdx.x * 64;

    // stage x tile (fp32 -> bf16, swizzled)
    for (int it = 0; it < 16; ++it) {
        int flat = it * 512 + t;
        int row = flat >> 7, c4 = flat & 127;
        float4 v = ((const float4*)(x + (r0 + row) * 512))[c4];
        bf16x4 h = { (bf16_t)v.x, (bf16_t)v.y, (bf16_t)v.z, (bf16_t)v.w };
        int byte = (row << 10) + (c4 << 3);
        byte ^= ((row & 7) << 4);
        *(bf16x4*)((char*)bufA + byte) = h;
    }
    __syncthreads();
    const int wave = t >> 6, lane = t & 63, l15 = lane & 15, lhi = lane >> 4;
    const int n0 = wave * 64;

    {   // layer 1: read A, write B
        f32x4 acc[4][4] = {};
        gemm_tile<512>(acc, bufA, 1024, W1b, n0, l15, lhi);
        epi_lds<true>(acc, b1, bufB, 1024, n0, l15, lhi);
    }
    __syncthreads();
    {   // layer 2: read B, write A
        f32x4 acc[4][4] = {};
        gemm_tile<512>(acc, bufB, 1024, W2b, n0, l15, lhi);
        epi_lds<true>(acc, b2, bufA, 1024, n0, l15, lhi);
    }
    __syncthreads();
    {   // heads: read A, write B (cols 0-255 mu, 256-511 lv)
        f32x4 acc[4][4] = {};
        gemm_tile<512>(acc, bufA, 1024, Hb, n0, l15, lhi);
        const float* hb = (n0 < 256) ? (mub + n0) : (lvb + n0 - 256);
#pragma unroll
        for (int cf = 0; cf < 4; ++cf) {
            const int cl = cf * 16 + lhi * 4;
            float4 b4 = *(const float4*)(hb + cl);
#pragma unroll
            for (int rf = 0; rf < 4; ++rf) {
                bf16x4 p = { (bf16_t)(acc[rf][cf][0] + b4.x), (bf16_t)(acc[rf][cf][1] + b4.y),
                             (bf16_t)(acc[rf][cf][2] + b4.z), (bf16_t)(acc[rf][cf][3] + b4.w) };
                lds_write8B(bufB, rf * 16 + l15, n0 + cl, 1024, p);
            }
        }
    }
    __syncthreads();

    // z = mu + eps * T^1.5 * exp(0.5*lv_raw)   (log-T folded); mu cols 0-255, lv 256-511 in bufB
    const int cc = (t & 63) * 4;
    const int ag = cc >> 6;
    const float tp = (ag == 0) ? 1.8371173070873836f
                   : (ag == 1) ? 0.35355339059327373f
                   : (ag == 2) ? 1.0f
                               : 0.7155417527999327f;
    const int rb = t >> 6;
    for (int it = 0; it < 8; ++it) {
        int row = it * 8 + rb;
        bf16x4 mu4 = lds_read8B(bufB, row, cc, 1024);
        bf16x4 lv4 = lds_read8B(bufB, row, cc + 256, 1024);
        float4 ep4 = *(const float4*)(eps + (r0 + row) * 256 + cc);
        bf16x4 zo;
        zo[0] = (bf16_t)fmaf(ep4.x * tp, expf(0.5f * (float)lv4[0]), (float)mu4[0]);
        zo[1] = (bf16_t)fmaf(ep4.y * tp, expf(0.5f * (float)lv4[1]), (float)mu4[1]);
        zo[2] = (bf16_t)fmaf(ep4.z * tp, expf(0.5f * (float)lv4[2]), (float)mu4[2]);
        zo[3] = (bf16_t)fmaf(ep4.w * tp, expf(0.5f * (float)lv4[3]), (float)mu4[3]);
        *(bf16x4*)(zout + (r0 + row) * 256 + cc) = zo;
    }
}

// ---------- kernel 3: attention over 4 agents + consensus (unchanged) ----------
__global__ __launch_bounds__(512) void attn_kernel(
    const bf16_t* __restrict__ z,
    const bf16_t* __restrict__ Wqkvb, const float* __restrict__ bqkv,
    const bf16_t* __restrict__ Wob,   const float* __restrict__ bo,
    const bf16_t* __restrict__ Wcb,   const float* __restrict__ bc,
    bf16_t* __restrict__ zcb)
{
    __shared__ bf16_t zt[256 * 64];    // z tile, later ctx tile   (rowB 128)
    __shared__ bf16_t qt[256 * 192];   // qkv tile, later z_att    (rowB 384/128)
    const int t = threadIdx.x;
    const size_t s0 = (size_t)blockIdx.x * 64;

    for (int it = 0; it < 4; ++it) {
        int ch = it * 512 + t;
        int r = ch >> 3, cc = ch & 7;
        bf16x8 v = *(const bf16x8*)(z + s0 * 256 + r * 64 + cc * 8);
        lds_write16B(zt, r, cc * 16, 128, v);
    }
    __syncthreads();
    const int wave = t >> 6, lane = t & 63, l15 = lane & 15, lhi = lane >> 4;
    const int rbase = wave * 32;

    for (int cc = 0; cc < 4; ++cc) {
        f32x4 acc[2][3] = {};
#pragma unroll
        for (int ks = 0; ks < 2; ++ks) {
            int k = ks * 32 + lhi * 8;
            bf16x8 a0 = lds_read8(zt, rbase + l15, k, 128);
            bf16x8 a1 = lds_read8(zt, rbase + 16 + l15, k, 128);
#pragma unroll
            for (int cf = 0; cf < 3; ++cf) {
                bf16x8 b = *(const bf16x8*)(Wqkvb + (cc * 48 + cf * 16 + l15) * 64 + k);
                acc[0][cf] = MFMA16(a0, b, acc[0][cf]);
                acc[1][cf] = MFMA16(a1, b, acc[1][cf]);
            }
        }
#pragma unroll
        for (int cf = 0; cf < 3; ++cf) {
            int col = cc * 48 + cf * 16 + l15;
            float bs = bqkv[col];
#pragma unroll
            for (int rf = 0; rf < 2; ++rf)
#pragma unroll
                for (int r = 0; r < 4; ++r)
                    lds_write1(qt, rbase + rf * 16 + lhi * 4 + r, col, 384, acc[rf][cf][r] + bs);
        }
    }
    __syncthreads();

    if (t < 256) {
        const int sl = t >> 2, head = t & 3;
        bf16x8 qv[4][2], kv[4][2], vv[4][2];
#pragma unroll
        for (int a2 = 0; a2 < 4; ++a2) {
            int r = sl * 4 + a2;
#pragma unroll
            for (int i = 0; i < 2; ++i) {
                qv[a2][i] = lds_read16B(qt, r, head * 32 + 16 * i, 384);
                kv[a2][i] = lds_read16B(qt, r, 128 + head * 32 + 16 * i, 384);
                vv[a2][i] = lds_read16B(qt, r, 256 + head * 32 + 16 * i, 384);
            }
        }
        float sc[4][4];
#pragma unroll
        for (int qa = 0; qa < 4; ++qa)
#pragma unroll
            for (int ka = 0; ka < 4; ++ka) {
                float s = 0.f;
#pragma unroll
                for (int i = 0; i < 2; ++i)
#pragma unroll
                    for (int j = 0; j < 8; ++j)
                        s += (float)qv[qa][i][j] * (float)kv[ka][i][j];
                sc[qa][ka] = s * 0.25f;
            }
#pragma unroll
        for (int qa = 0; qa < 4; ++qa) {
            float m = fmaxf(fmaxf(sc[qa][0], sc[qa][1]), fmaxf(sc[qa][2], sc[qa][3]));
            float e[4], sum = 0.f;
#pragma unroll
            for (int ka = 0; ka < 4; ++ka) { e[ka] = expf(sc[qa][ka] - m); sum += e[ka]; }
            float inv = 1.f / sum;
#pragma unroll
            for (int i = 0; i < 2; ++i) {
                bf16x8 cv;
#pragma unroll
                for (int j = 0; j < 8; ++j) {
                    float cval = 0.f;
#pragma unroll
                    for (int ka = 0; ka < 4; ++ka) cval += e[ka] * inv * (float)vv[ka][i][j];
                    cv[j] = (bf16_t)cval;
                }
                lds_write16B(zt, sl * 4 + qa, head * 32 + 16 * i, 128, cv);
            }
        }
    }
    __syncthreads();

    {   // z_att = ctx @ Wo^T + bo
        f32x4 acc[2][4] = {};
#pragma unroll
        for (int ks = 0; ks < 2; ++ks) {
            int k = ks * 32 + lhi * 8;
            bf16x8 a0 = lds_read8(zt, rbase + l15, k, 128);
            bf16x8 a1 = lds_read8(zt, rbase + 16 + l15, k, 128);
#pragma unroll
            for (int cf = 0; cf < 4; ++cf) {
                bf16x8 b = *(const bf16x8*)(Wob + (cf * 16 + l15) * 64 + k);
                acc[0][cf] = MFMA16(a0, b, acc[0][cf]);
                acc[1][cf] = MFMA16(a1, b, acc[1][cf]);
            }
        }
        __syncthreads();
#pragma unroll
        for (int cf = 0; cf < 4; ++cf) {
            int col = cf * 16 + l15;
            float bs = bo[col];
#pragma unroll
            for (int rf = 0; rf < 2; ++rf)
#pragma unroll
                for (int r = 0; r < 4; ++r)
                    lds_write1(qt, rbase + rf * 16 + lhi * 4 + r, col, 128, acc[rf][cf][r] + bs);
        }
    }
    __syncthreads();

    {   // z_consensus = z_att.reshape(64,256) @ Wc^T + bc
        f32x4 acc2[2] = {};
        const int rfw = wave >> 1, cbase = (wave & 1) * 2;
        const int srow = rfw * 16 + l15;
#pragma unroll
        for (int ks = 0; ks < 8; ++ks) {
            int k = ks * 32 + lhi * 8;
            int byte = (srow << 9) + (k << 1);
            byte ^= ((((srow << 2) + (k >> 6)) & 7) << 4);
            bf16x8 a = *(const bf16x8*)((const char*)qt + byte);
#pragma unroll
            for (int i = 0; i < 2; ++i) {
                bf16x8 b = *(const bf16x8*)(Wcb + ((cbase + i) * 16 + l15) * 256 + k);
                acc2[i] = MFMA16(a, b, acc2[i]);
            }
        }
#pragma unroll
        for (int i = 0; i < 2; ++i) {
            int col = (cbase + i) * 16 + l15;
            float bs = bc[col];
#pragma unroll
            for (int r = 0; r < 4; ++r) {
                int s = (int)(s0) + rfw * 16 + lhi * 4 + r;
                zcb[(size_t)s * 64 + col] = (bf16_t)(acc2[i][r] + bs);
            }
        }
    }
}

// ---------- kernel 4: fused 3-layer decoder ----------
__global__ __launch_bounds__(512, 2) void dec_kernel(
    const bf16_t* __restrict__ z, const bf16_t* __restrict__ zc,
    const bf16_t* __restrict__ Wd1b, const float* __restrict__ bd1,
    const bf16_t* __restrict__ Wd2b, const float* __restrict__ bd2,
    const bf16_t* __restrict__ Wd3b, const float* __restrict__ bd3,
    float* __restrict__ out)
{
    __shared__ bf16_t zz[64 * 64];      // 8KB latent tile
    __shared__ bf16_t bufA[64 * 512];   // ping
    __shared__ bf16_t bufB[64 * 512];   // pong
    const int t = threadIdx.x;
    const long r0 = (long)blockIdx.x * 64;

    {   // gather latent rows: row = s*5 + j; j==0 -> consensus, else agent j-1
        int row = t >> 3, ch = t & 7;
        long rg = r0 + row;
        int s = (int)(rg / 5);
        int j = (int)(rg - (long)s * 5);
        const bf16_t* src = (j == 0) ? (zc + (size_t)s * 64)
                                     : (z + (size_t)s * 256 + (j - 1) * 64);
        bf16x8 v = *(const bf16x8*)(src + ch * 8);
        int byte = (row << 7) + (ch << 4);
        byte ^= ((row & 7) << 4);
        *(bf16x8*)((char*)zz + byte) = v;
    }
    __syncthreads();
    const int wave = t >> 6, lane = t & 63, l15 = lane & 15, lhi = lane >> 4;
    const int n0 = wave * 64;

    {   // layer 1: K=64 from zz -> bufA
        f32x4 acc[4][4] = {};
        gemm_tile<64>(acc, zz, 128, Wd1b, n0, l15, lhi);
        epi_lds<true>(acc, bd1, bufA, 1024, n0, l15, lhi);
    }
    __syncthreads();
    {   // layer 2: bufA -> bufB
        f32x4 acc[4][4] = {};
        gemm_tile<512>(acc, bufA, 1024, Wd2b, n0, l15, lhi);
        epi_lds<true>(acc, bd2, bufB, 1024, n0, l15, lhi);
    }
    __syncthreads();
    {   // layer 3: bufB -> global fp32 (float4 coalesced)
        f32x4 acc[4][4] = {};
        gemm_tile<512>(acc, bufB, 1024, Wd3b, n0, l15, lhi);
        epi_global(acc, bd3, out, r0, n0, l15, lhi);
    }
}

// ---------- launcher ----------
extern "C" void kernel_launch(void* const* d_in, const int* in_sizes, int n_in,
                              void* d_out, int out_size, void* d_ws, size_t ws_size,
                              hipStream_t stream) {
    const float* x    = (const float*)d_in[0];
    const float* eps  = (const float*)d_in[1];
    const float* W1   = (const float*)d_in[2];
    const float* b1   = (const float*)d_in[3];
    const float* W2   = (const float*)d_in[4];
    const float* b2   = (const float*)d_in[5];
    const float* muW  = (const float*)d_in[6];
    const float* mub  = (const float*)d_in[7];
    const float* lvW  = (const float*)d_in[8];
    const float* lvb  = (const float*)d_in[9];
    const float* Wqkv = (const float*)d_in[10];
    const float* bqkv = (const float*)d_in[11];
    const float* Wo   = (const float*)d_in[12];
    const float* bo   = (const float*)d_in[13];
    const float* Wc   = (const float*)d_in[14];
    const float* bc   = (const float*)d_in[15];
    const float* Wd1  = (const float*)d_in[16];
    const float* bd1  = (const float*)d_in[17];
    const float* Wd2  = (const float*)d_in[18];
    const float* bd2  = (const float*)d_in[19];
    const float* Wd3  = (const float*)d_in[20];
    const float* bd3  = (const float*)d_in[21];
    float* out = (float*)d_out;

    bf16_t* wsb  = (bf16_t*)d_ws;
    bf16_t* W1b  = wsb + 0;
    bf16_t* W2b  = wsb + 262144;
    bf16_t* Hb   = wsb + 524288;    // [muW(256x512) ; lvW(256x512)]
    bf16_t* Wqkvb= wsb + 786432;
    bf16_t* Wob  = wsb + 798720;
    bf16_t* Wcb  = wsb + 802816;
    bf16_t* Wd1b = wsb + 819200;
    bf16_t* Wd2b = wsb + 851968;
    bf16_t* Wd3b = wsb + 1114112;
    bf16_t* zbuf = wsb + 1376256;   // (B,256) bf16
    bf16_t* zcb  = wsb + 9764864;   // (B,64)  bf16

    cast_kernel<<<dim3(5376), dim3(256), 0, stream>>>(
        W1, W2, muW, lvW, Wqkv, Wo, Wc, Wd1, Wd2, Wd3, wsb);
    enc_kernel<<<dim3(512), dim3(512), 0, stream>>>(
        x, eps, W1b, b1, W2b, b2, Hb, mub, lvb, zbuf);
    attn_kernel<<<dim3(512), dim3(512), 0, stream>>>(
        zbuf, Wqkvb, bqkv, Wob, bo, Wcb, bc, zcb);
    dec_kernel<<<dim3(2560), dim3(512), 0, stream>>>(
        zbuf, zcb, Wd1b, bd1, Wd2b, bd2, Wd3b, bd3, out);
}